// Round 2
// baseline (5551.837 us; speedup 1.0000x reference)
//
#include <hip/hip_runtime.h>
#include <hip/hip_bf16.h>

// Problem dims
static const int kB = 128, kN = 49, kC = 2048, kD = 512, kE = 512, kV = 10000, kT = 20;

__device__ __forceinline__ float sigmoidf_(float x){ return 1.f/(1.f+expf(-x)); }

// ---------------- general fp32 NT GEMM: C = act(A@W^T + bias + add1 + add2) ----------------
// A: [M,K] lda, W: [N,K] ldw (dot along contiguous K), C: [M,N] ldc
#define GBM 64
#define GBN 64
#define GBK 16

__global__ __launch_bounds__(256) void gemm_nt(
    const float* __restrict__ A, int lda,
    const float* __restrict__ W, int ldw,
    float* __restrict__ C, int ldc,
    int M, int N, int K,
    const float* __restrict__ bias,
    const float* __restrict__ add1, int ld1,
    const float* __restrict__ add2, int ld2,
    int act)
{
    __shared__ float As[GBK][GBM];
    __shared__ float Bs[GBK][GBN];
    const int tid = threadIdx.x;
    const int bm = blockIdx.y * GBM;
    const int bn = blockIdx.x * GBN;
    const int tx = tid & 15, ty = tid >> 4;
    const int lr = tid >> 2;          // 0..63 tile row
    const int lk = (tid & 3) << 2;    // 0,4,8,12
    float acc[4][4] = {};
    for (int k0 = 0; k0 < K; k0 += GBK) {
        float4 av = make_float4(0.f,0.f,0.f,0.f), wv = make_float4(0.f,0.f,0.f,0.f);
        int gm = bm + lr;
        if (gm < M) av = *(const float4*)(A + (size_t)gm*lda + k0 + lk);
        int gn = bn + lr;
        if (gn < N) wv = *(const float4*)(W + (size_t)gn*ldw + k0 + lk);
        As[lk+0][lr]=av.x; As[lk+1][lr]=av.y; As[lk+2][lr]=av.z; As[lk+3][lr]=av.w;
        Bs[lk+0][lr]=wv.x; Bs[lk+1][lr]=wv.y; Bs[lk+2][lr]=wv.z; Bs[lk+3][lr]=wv.w;
        __syncthreads();
        #pragma unroll
        for (int kk = 0; kk < GBK; ++kk) {
            float4 a4 = *(const float4*)&As[kk][ty<<2];
            float4 b4 = *(const float4*)&Bs[kk][tx<<2];
            float a[4] = {a4.x,a4.y,a4.z,a4.w};
            float b[4] = {b4.x,b4.y,b4.z,b4.w};
            #pragma unroll
            for (int i=0;i<4;i++)
                #pragma unroll
                for (int j=0;j<4;j++)
                    acc[i][j] = fmaf(a[i], b[j], acc[i][j]);
        }
        __syncthreads();
    }
    #pragma unroll
    for (int i=0;i<4;i++){
        int m = bm + (ty<<2) + i;
        if (m >= M) continue;
        #pragma unroll
        for (int j=0;j<4;j++){
            int n = bn + (tx<<2) + j;
            if (n >= N) continue;
            float v = acc[i][j];
            if (bias) v += bias[n];
            if (add1) v += add1[(size_t)m*ld1 + n];
            if (add2) v += add2[(size_t)m*ld2 + n];
            if (act==1) v = fmaxf(v, 0.f);
            else if (act==2) v = tanhf(v);
            else if (act==3) v = sigmoidf_(v);
            C[(size_t)m*ldc + n] = v;
        }
    }
}

// ---------------- small pointwise / helper kernels ----------------
__global__ __launch_bounds__(256) void mean_k(const float* __restrict__ img, float* __restrict__ meanp){
    int idx = blockIdx.x*256 + threadIdx.x;       // B*C
    int b = idx >> 11, c = idx & (kC-1);
    const float* p = img + (size_t)b*kN*kC + c;
    float s = 0.f;
    #pragma unroll
    for (int n=0;n<kN;n++) s += p[(size_t)n*kC];
    meanp[idx] = s * (1.f/(float)kN);
}

__global__ __launch_bounds__(256) void emb_gather_k(const int* __restrict__ target,
                                                    const float* __restrict__ emb,
                                                    float* __restrict__ we){
    int idx = blockIdx.x*256 + threadIdx.x;       // B*T*E
    int e = idx & (kE-1);
    int r = idx >> 9;                             // b*T + t
    int t = r % kT, b = r / kT;
    float v = 0.f;
    if (t > 0){ int tok = target[b*kT + (t-1)]; v = emb[(size_t)tok*kE + e]; }
    we[idx] = v;
}

__global__ __launch_bounds__(256) void bsum_k(const float* __restrict__ a, const float* __restrict__ b,
                                              float* __restrict__ o, int n){
    int i = blockIdx.x*256 + threadIdx.x;
    if (i < n) o[i] = a[i] + b[i];
}

__global__ __launch_bounds__(256) void lstm_k(
    const float* __restrict__ gates, const float* __restrict__ gtpre,
    const float* __restrict__ m_in, float* __restrict__ h_out,
    float* __restrict__ m_out, float* __restrict__ gtv)
{
    int idx = blockIdx.x*256 + threadIdx.x;       // B*D
    int b = idx >> 9, d = idx & (kD-1);
    const float* g = gates + (size_t)b*4*kD;
    float vi = sigmoidf_(g[d]);
    float vf = sigmoidf_(g[kD+d]);
    float vg = tanhf(g[2*kD+d]);
    float vo = sigmoidf_(g[3*kD+d]);
    float m2 = vf*m_in[idx] + vi*vg;
    float tm = tanhf(m2);
    h_out[idx] = vo*tm;
    m_out[idx] = m2;
    gtv[idx] = sigmoidf_(gtpre[idx]) * tm;
}

// Fused attention step: gH, sWs, z, z2, softmax(50), attn-out, ctx, Hc=H+ctx. One block per b.
__global__ __launch_bounds__(256) void attn_step(
    const float* __restrict__ Hbuf, const float* __restrict__ sbuf,
    const float* __restrict__ Wg, const float* __restrict__ Wsm,
    const float* __restrict__ wh, const float* __restrict__ zbase,
    const float* __restrict__ Vf, float* __restrict__ Hc,
    float* __restrict__ attn_out, int t)
{
    const int b = blockIdx.x, tid = threadIdx.x;
    __shared__ float shH[kD], shS[kD];
    __shared__ float shgH[64], shsWs[64], shwh[64], shz[64], shzb[64];
    __shared__ float shpart[4][64];
    __shared__ float shalpha[64];
    for (int i = tid; i < kD; i += 256){ shH[i]=Hbuf[b*kD+i]; shS[i]=sbuf[b*kD+i]; }
    if (tid < kN) shwh[tid] = wh[tid];
    __syncthreads();
    // gH[n] = H[b]·Wg[n], sWs[n] = s[b]·Ws[n]
    if (tid < kN){
        float acc = 0.f;
        #pragma unroll 8
        for (int k=0;k<kD;k++) acc += shH[k]*Wg[tid*kD+k];
        shgH[tid] = acc;
    } else if (tid >= 64 && tid < 64+kN){
        int n = tid-64; float acc = 0.f;
        #pragma unroll 8
        for (int k=0;k<kD;k++) acc += shS[k]*Wsm[n*kD+k];
        shsWs[n] = acc;
    }
    __syncthreads();
    // z[n] = sum_k tanh(zbase[b,n,k]+gH[k])*wh[k]  (4-way k-split)
    {
        int n = tid & 63, j = tid >> 6;
        float p = 0.f;
        if (n < kN){
            const float* zb = zbase + ((size_t)b*kN + n)*kN;
            for (int k=j;k<kN;k+=4) p += tanhf(zb[k]+shgH[k])*shwh[k];
        }
        shpart[j][n] = p;
    }
    __syncthreads();
    if (tid < kN){
        shz[tid] = shpart[0][tid]+shpart[1][tid]+shpart[2][tid]+shpart[3][tid];
    } else if (tid >= 64 && tid < 64+kN){
        int n = tid-64;
        shzb[n] = tanhf(shsWs[n]+shgH[n])*shwh[n];
    }
    __syncthreads();
    // softmax over [z(49), z2] in wave 0
    if (tid < 64){
        float val;
        if (tid < kN) val = shz[tid];
        else if (tid == kN){ float a=0.f; for (int n2=0;n2<kN;n2++) a += shzb[n2]; val = a; }
        else val = -1e30f;
        float mx = val;
        #pragma unroll
        for (int o=32;o>0;o>>=1) mx = fmaxf(mx, __shfl_xor(mx, o));
        float e = (tid <= kN) ? expf(val-mx) : 0.f;
        float ssum = e;
        #pragma unroll
        for (int o=32;o>0;o>>=1) ssum += __shfl_xor(ssum, o);
        float a = e/ssum;
        if (tid <= kN) shalpha[tid] = a;
        if (tid < kN) attn_out[((size_t)b*kT + t)*kN + tid] = a;
    }
    __syncthreads();
    // ctx + H
    for (int d = tid; d < kD; d += 256){
        float acc = shalpha[kN]*shS[d];
        const float* vf = Vf + (size_t)b*kN*kD + d;
        #pragma unroll
        for (int n2=0;n2<kN;n2++) acc += shalpha[n2]*vf[(size_t)n2*kD];
        Hc[b*kD+d] = shH[d] + acc;
    }
}

// in-place log-softmax over rows of [B*T, V] fp32
__global__ __launch_bounds__(256) void logsoftmax_k(float* __restrict__ logits)
{
    const int row = blockIdx.x, tid = threadIdx.x;
    float* L = logits + (size_t)row*kV;
    __shared__ float red[256];
    float m = -1e30f;
    for (int v=tid; v<kV; v+=256) m = fmaxf(m, L[v]);
    red[tid] = m; __syncthreads();
    for (int s2=128; s2>0; s2>>=1){ if (tid<s2) red[tid]=fmaxf(red[tid],red[tid+s2]); __syncthreads(); }
    float mx = red[0]; __syncthreads();
    float ss = 0.f;
    for (int v=tid; v<kV; v+=256) ss += expf(L[v]-mx);
    red[tid] = ss; __syncthreads();
    for (int s2=128; s2>0; s2>>=1){ if (tid<s2) red[tid]+=red[tid+s2]; __syncthreads(); }
    float lse = mx + logf(red[0]);
    for (int v=tid; v<kV; v+=256) L[v] = L[v]-lse;
}

extern "C" void kernel_launch(void* const* d_in, const int* in_sizes, int n_in,
                              void* d_out, int out_size, void* d_ws, size_t ws_size,
                              hipStream_t stream)
{
    const float* img   = (const float*)d_in[0];
    const int*   target= (const int*)  d_in[1];
    const float* emb   = (const float*)d_in[2];
    const float* Wa    = (const float*)d_in[3];
    const float* ba    = (const float*)d_in[4];
    const float* Wb    = (const float*)d_in[5];
    const float* bb    = (const float*)d_in[6];
    const float* Whi   = (const float*)d_in[7];
    const float* bhi   = (const float*)d_in[8];
    const float* Wmi   = (const float*)d_in[9];
    const float* bmi   = (const float*)d_in[10];
    const float* Wih   = (const float*)d_in[11];
    const float* bih   = (const float*)d_in[12];
    const float* Whh   = (const float*)d_in[13];
    const float* bhh   = (const float*)d_in[14];
    const float* Wv    = (const float*)d_in[15];
    const float* Wg    = (const float*)d_in[16];
    const float* wh    = (const float*)d_in[17];
    const float* W_H   = (const float*)d_in[18];
    const float* Wx    = (const float*)d_in[19];
    const float* Wh2   = (const float*)d_in[20];
    const float* Wsm   = (const float*)d_in[21];
    const float* Wc    = (const float*)d_in[22];
    const float* bc    = (const float*)d_in[23];
    const float* Wfc   = (const float*)d_in[24];
    const float* bfc   = (const float*)d_in[25];
    const float* Wp    = (const float*)d_in[26];
    const float* bp    = (const float*)d_in[27];
    (void)in_sizes; (void)n_in; (void)out_size; (void)ws_size;

    // fp32 outputs: logprobs [B*T, V] then attn [B, T, N]
    float* out0 = (float*)d_out;
    float* attn_out = out0 + (size_t)kB*kT*kV;

    // workspace bump allocation (floats), 256B aligned
    char* base = (char*)d_ws;
    size_t off = 0;
    auto alloc = [&](size_t nfloats)->float*{
        float* p = (float*)(base + off);
        off += ((nfloats*sizeof(float) + 255) & ~(size_t)255);
        return p;
    };
    float* meanb   = alloc((size_t)kB*kC);
    float* vg      = alloc((size_t)kB*kD);
    float* hbuf0   = alloc((size_t)kB*kD);
    float* hbuf1   = alloc((size_t)kB*kD);
    float* mbuf0   = alloc((size_t)kB*kD);
    float* mbuf1   = alloc((size_t)kB*kD);
    float* Vf      = alloc((size_t)kB*kN*kD);
    float* zbase   = alloc((size_t)kB*kN*kN);
    float* we_all  = alloc((size_t)kB*kT*kE);
    float* gemb    = alloc((size_t)kB*kT*4*kD);
    float* gtemb   = alloc((size_t)kB*kT*kD);
    float* gxbase  = alloc((size_t)kB*4*kD);
    float* gtbase  = alloc((size_t)kB*kD);
    float* bsum    = alloc((size_t)4*kD);
    float* gates   = alloc((size_t)kB*4*kD);
    float* gtpre   = alloc((size_t)kB*kD);
    float* gtv     = alloc((size_t)kB*kD);
    float* Hb      = alloc((size_t)kB*kD);
    float* sb      = alloc((size_t)kB*kD);
    float* Hc      = alloc((size_t)kB*kD);
    float* outAll  = alloc((size_t)kB*kT*kD);

    auto gemm = [&](const float* A,int lda,const float* W,int ldw,float* C,int ldc,
                    int M,int N,int K,const float* bias,
                    const float* a1,int l1,const float* a2,int l2,int act){
        dim3 g((N+GBN-1)/GBN, (M+GBM-1)/GBM);
        hipLaunchKernelGGL(gemm_nt, g, dim3(256), 0, stream,
                           A,lda,W,ldw,C,ldc,M,N,K,bias,a1,l1,a2,l2,act);
    };

    // ---------------- precompute ----------------
    hipLaunchKernelGGL(mean_k, dim3(kB*kC/256), dim3(256), 0, stream, img, meanb);
    gemm(meanb, kC, Wb,  kC, vg,    kD, kB, kD, kC, bb,  nullptr,0, nullptr,0, 1);
    gemm(meanb, kC, Whi, kC, hbuf0, kD, kB, kD, kC, bhi, nullptr,0, nullptr,0, 1);
    gemm(meanb, kC, Wmi, kC, mbuf0, kD, kB, kD, kC, bmi, nullptr,0, nullptr,0, 1);
    gemm(img,   kC, Wa,  kC, Vf,    kD, kB*kN, kD, kC, ba, nullptr,0, nullptr,0, 1);
    gemm(Vf,    kD, Wv,  kD, zbase, kN, kB*kN, kN, kD, nullptr, nullptr,0, nullptr,0, 0);
    hipLaunchKernelGGL(emb_gather_k, dim3(kB*kT*kE/256), dim3(256), 0, stream, target, emb, we_all);
    gemm(we_all, kE, Wih+kD, kD+kE, gemb,  4*kD, kB*kT, 4*kD, kE, nullptr, nullptr,0, nullptr,0, 0);
    gemm(we_all, kE, Wx +kD, kD+kE, gtemb, kD,   kB*kT, kD,   kE, nullptr, nullptr,0, nullptr,0, 0);
    hipLaunchKernelGGL(bsum_k, dim3((4*kD+255)/256), dim3(256), 0, stream, bih, bhh, bsum, 4*kD);
    gemm(vg, kD, Wih, kD+kE, gxbase, 4*kD, kB, 4*kD, kD, bsum,    nullptr,0, nullptr,0, 0);
    gemm(vg, kD, Wx,  kD+kE, gtbase, kD,   kB, kD,   kD, nullptr, nullptr,0, nullptr,0, 0);

    // ---------------- recurrent scan ----------------
    for (int t = 0; t < kT; ++t){
        const float* hc = (t & 1) ? hbuf1 : hbuf0;
        float*       hn = (t & 1) ? hbuf0 : hbuf1;
        const float* mc = (t & 1) ? mbuf1 : mbuf0;
        float*       mn = (t & 1) ? mbuf0 : mbuf1;
        // gates = h@Whh^T + gxbase + gemb[:,t]
        gemm(hc, kD, Whh, kD, gates, 4*kD, kB, 4*kD, kD, nullptr,
             gxbase, 4*kD, gemb + (size_t)t*4*kD, kT*4*kD, 0);
        // gtpre = hp@Wh2^T + gtbase + gtemb[:,t]
        gemm(hc, kD, Wh2, kD, gtpre, kD, kB, kD, kD, nullptr,
             gtbase, kD, gtemb + (size_t)t*kD, kT*kD, 0);
        hipLaunchKernelGGL(lstm_k, dim3(kB*kD/256), dim3(256), 0, stream,
                           gates, gtpre, mc, hn, mn, gtv);
        // H = relu(h2@WH^T); s = relu(gtv@Wc^T + bc)
        gemm(hn,  kD, W_H, kD, Hb, kD, kB, kD, kD, nullptr, nullptr,0, nullptr,0, 1);
        gemm(gtv, kD, Wc,  kD, sb, kD, kB, kD, kD, bc,      nullptr,0, nullptr,0, 1);
        hipLaunchKernelGGL(attn_step, dim3(kB), dim3(256), 0, stream,
                           Hb, sb, Wg, Wsm, wh, zbase, Vf, Hc, attn_out, t);
        // out[:,t] = tanh(Hc@Wfc^T + bfc)
        gemm(Hc, kD, Wfc, kD, outAll + (size_t)t*kD, kT*kD, kB, kD, kD, bfc,
             nullptr,0, nullptr,0, 2);
    }

    // ---------------- logits into d_out (fp32) + in-place log_softmax ----------------
    gemm(outAll, kD, Wp, kD, out0, kV, kB*kT, kV, kD, bp, nullptr,0, nullptr,0, 0);
    hipLaunchKernelGGL(logsoftmax_k, dim3(kB*kT), dim3(256), 0, stream, out0);
}

// Round 3
// 3431.676 us; speedup vs baseline: 1.6178x; 1.6178x over previous
//
#include <hip/hip_runtime.h>
#include <hip/hip_bf16.h>

// Problem dims
static const int kB = 128, kN = 49, kC = 2048, kD = 512, kE = 512, kV = 10000, kT = 20;

typedef __bf16 bf16x8 __attribute__((ext_vector_type(8)));
typedef float  f32x4v __attribute__((ext_vector_type(4)));
typedef unsigned short u16;

__device__ __forceinline__ float sigmoidf_(float x){ return 1.f/(1.f+expf(-x)); }
__device__ __forceinline__ u16 f2b(float x){ __hip_bfloat16 h = __float2bfloat16(x); return *(u16*)&h; }

// ================= bf16 MFMA NT GEMM =================
// C[M,N] = act(A[M,K] @ W[N,K]^T + bias + add1), fp32 accumulate.
// A can be fp32 (a_f32=1, converted during staging) or bf16.
// Dual-A: blocks with bn >= nsplit read A2 instead (same lda).
// add1 row index is (m & a1mask)  (a1mask=-1: identity; 127: broadcast over b).
// rowmap=1 permutes the store row: m=(t*128+b) -> b*20+t  (for logits).
#define TBM 128
#define TBN 128
#define TBK 32

__global__ __launch_bounds__(256) void gemm_bf16(
    const void* __restrict__ Aptr, const void* __restrict__ A2ptr, int nsplit,
    int lda, int a_f32,
    const u16* __restrict__ W, int ldw,
    float* __restrict__ C, int ldc, u16* __restrict__ Cbf,
    int M, int N, int K,
    const float* __restrict__ bias,
    const float* __restrict__ add1, int ld1, int a1mask,
    int act, int rowmap)
{
    __shared__ __align__(16) u16 As[TBM*TBK];
    __shared__ __align__(16) u16 Bs[TBN*TBK];
    const int tid = threadIdx.x;
    const int bm = blockIdx.y * TBM;
    const int bn = blockIdx.x * TBN;
    const u16*   Ab = (const u16*)  ((bn >= nsplit) ? A2ptr : Aptr);
    const float* Af = (const float*)((bn >= nsplit) ? A2ptr : Aptr);
    const int wave = tid >> 6, lane = tid & 63;
    const int wm = (wave >> 1) * 64, wn = (wave & 1) * 64;
    const int lm = lane & 15, quad = lane >> 4;
    const int r = tid >> 2, koff = (tid & 3) * 8;
    f32x4v acc[4][4] = {};
    for (int k0 = 0; k0 < K; k0 += TBK) {
        #pragma unroll
        for (int h = 0; h < 2; ++h) {
            int row = r + h*64;
            bf16x8 av = {};
            int gm = bm + row;
            if (gm < M) {
                if (a_f32) {
                    const float* p = Af + (size_t)gm*lda + k0 + koff;
                    f32x4v f0 = *(const f32x4v*)p;
                    f32x4v f1 = *(const f32x4v*)(p + 4);
                    av[0]=(__bf16)f0[0]; av[1]=(__bf16)f0[1]; av[2]=(__bf16)f0[2]; av[3]=(__bf16)f0[3];
                    av[4]=(__bf16)f1[0]; av[5]=(__bf16)f1[1]; av[6]=(__bf16)f1[2]; av[7]=(__bf16)f1[3];
                } else {
                    av = *(const bf16x8*)(Ab + (size_t)gm*lda + k0 + koff);
                }
            }
            *(bf16x8*)&As[row*TBK + koff] = av;
            bf16x8 wv = {};
            int gn = bn + row;
            if (gn < N) wv = *(const bf16x8*)(W + (size_t)gn*ldw + k0 + koff);
            *(bf16x8*)&Bs[row*TBK + koff] = wv;
        }
        __syncthreads();
        bf16x8 afr[4], bfr[4];
        #pragma unroll
        for (int i = 0; i < 4; ++i) afr[i] = *(const bf16x8*)&As[(wm + i*16 + lm)*TBK + quad*8];
        #pragma unroll
        for (int j = 0; j < 4; ++j) bfr[j] = *(const bf16x8*)&Bs[(wn + j*16 + lm)*TBK + quad*8];
        #pragma unroll
        for (int i = 0; i < 4; ++i)
            #pragma unroll
            for (int j = 0; j < 4; ++j)
                acc[i][j] = __builtin_amdgcn_mfma_f32_16x16x32_bf16(afr[i], bfr[j], acc[i][j], 0, 0, 0);
        __syncthreads();
    }
    // Epilogue. C/D layout: col = lane&15, row = quad*4 + reg  [measured m89/m91]
    #pragma unroll
    for (int i = 0; i < 4; ++i) {
        int mbase = bm + wm + i*16 + quad*4;
        #pragma unroll
        for (int j = 0; j < 4; ++j) {
            int n = bn + wn + j*16 + lm;
            if (n >= N) continue;
            float bv = bias ? bias[n] : 0.f;
            #pragma unroll
            for (int rr2 = 0; rr2 < 4; ++rr2) {
                int m = mbase + rr2;
                if (m >= M) continue;
                float v = acc[i][j][rr2] + bv;
                if (add1) v += add1[(size_t)(m & a1mask)*ld1 + n];
                if (act == 1) v = fmaxf(v, 0.f);
                else if (act == 2) v = tanhf(v);
                int mo = rowmap ? ((m & 127)*kT + (m >> 7)) : m;
                C[(size_t)mo*ldc + n] = v;
                if (Cbf) Cbf[(size_t)mo*ldc + n] = f2b(v);
            }
        }
    }
}

// ================= small helpers =================
__global__ __launch_bounds__(256) void mean_k(const float* __restrict__ img, float* __restrict__ meanp){
    int idx = blockIdx.x*256 + threadIdx.x;       // B*C
    int b = idx >> 11, c = idx & (kC-1);
    const float* p = img + (size_t)b*kN*kC + c;
    float s = 0.f;
    #pragma unroll
    for (int n = 0; n < kN; ++n) s += p[(size_t)n*kC];
    meanp[idx] = s * (1.f/(float)kN);
}

__global__ __launch_bounds__(256) void f2bf_k(const float* __restrict__ src, u16* __restrict__ dst, int n4){
    int i = blockIdx.x*256 + threadIdx.x;
    if (i < n4){
        f32x4v f = *(const f32x4v*)(src + 4*(size_t)i);
        union { u16 u[4]; uint2 v; } pk;
        pk.u[0]=f2b(f[0]); pk.u[1]=f2b(f[1]); pk.u[2]=f2b(f[2]); pk.u[3]=f2b(f[3]);
        *(uint2*)(dst + 4*(size_t)i) = pk.v;
    }
}

__global__ __launch_bounds__(256) void copy_k(const float* __restrict__ s, float* __restrict__ d, int n){
    int i = blockIdx.x*256 + threadIdx.x; if (i < n) d[i] = s[i];
}
__global__ __launch_bounds__(256) void zero_k(float* __restrict__ d, int n){
    int i = blockIdx.x*256 + threadIdx.x; if (i < n) d[i] = 0.f;
}
__global__ __launch_bounds__(256) void bsum_k(const float* __restrict__ a, const float* __restrict__ b,
                                              float* __restrict__ o, int n){
    int i = blockIdx.x*256 + threadIdx.x; if (i < n) o[i] = a[i] + b[i];
}

// we[t*B+b][e] = (t>0) ? emb[target[b][t-1]][e] : 0   (bf16 out)
__global__ __launch_bounds__(256) void emb_gather_k(const int* __restrict__ target,
                                                    const float* __restrict__ emb,
                                                    u16* __restrict__ we){
    int idx = blockIdx.x*256 + threadIdx.x;       // T*B*E
    int e = idx & (kE-1);
    int rr = idx >> 9;                            // t*B + b
    int b = rr & 127, t = rr >> 7;
    float v = 0.f;
    if (t > 0){ int tok = target[b*kT + (t-1)]; v = emb[(size_t)tok*kE + e]; }
    we[idx] = f2b(v);
}

// LSTM pointwise. gates layout per b: [i(512) f(512) g(512) o(512) gtpre(512)]
__global__ __launch_bounds__(256) void lstm_k(
    const float* __restrict__ gates, const float* __restrict__ m_in, int ldm,
    float* __restrict__ m_out, u16* __restrict__ h_bf, u16* __restrict__ gtv_bf)
{
    int idx = blockIdx.x*256 + threadIdx.x;       // B*D
    int b = idx >> 9, d = idx & (kD-1);
    const float* g = gates + (size_t)b*2560;
    float vi = sigmoidf_(g[d]);
    float vf = sigmoidf_(g[512+d]);
    float vg = tanhf(g[1024+d]);
    float vo = sigmoidf_(g[1536+d]);
    float gtp = g[2048+d];
    float m2 = vf * m_in[(size_t)b*ldm + d] + vi*vg;
    float tm = tanhf(m2);
    m_out[(size_t)b*kD + d] = m2;
    h_bf[(size_t)b*kD + d]  = f2b(vo*tm);
    gtv_bf[(size_t)b*kD + d] = f2b(sigmoidf_(gtp)*tm);
}

// Fused attention step + out = tanh((H+ctx)@Wfc^T + bfc). One block per b.
// HS: [B][1024] = [H | s]
__global__ __launch_bounds__(256) void attn_step(
    const float* __restrict__ HS,
    const float* __restrict__ Wg, const float* __restrict__ Wsm,
    const float* __restrict__ wh, const float* __restrict__ zbase,
    const float* __restrict__ Vf,
    const float* __restrict__ Wfc, const float* __restrict__ bfc,
    u16* __restrict__ out_bf, float* __restrict__ attn_out, int t)
{
    const int b = blockIdx.x, tid = threadIdx.x;
    __shared__ float shH[kD], shS[kD], shHc[kD];
    __shared__ float shgH[64], shsWs[64], shwh[64], shz[64], shzb[64];
    __shared__ float shpart[4][64];
    __shared__ float shalpha[64];
    for (int i = tid; i < kD; i += 256){ shH[i] = HS[(size_t)b*1024 + i]; shS[i] = HS[(size_t)b*1024 + 512 + i]; }
    if (tid < kN) shwh[tid] = wh[tid];
    __syncthreads();
    if (tid < kN){
        float acc = 0.f;
        #pragma unroll 8
        for (int k = 0; k < kD; ++k) acc += shH[k]*Wg[tid*kD + k];
        shgH[tid] = acc;
    } else if (tid >= 64 && tid < 64 + kN){
        int n = tid - 64; float acc = 0.f;
        #pragma unroll 8
        for (int k = 0; k < kD; ++k) acc += shS[k]*Wsm[n*kD + k];
        shsWs[n] = acc;
    }
    __syncthreads();
    {
        int n = tid & 63, j = tid >> 6;
        float p = 0.f;
        if (n < kN){
            const float* zb = zbase + ((size_t)b*kN + n)*kN;
            for (int k = j; k < kN; k += 4) p += tanhf(zb[k] + shgH[k])*shwh[k];
        }
        shpart[j][n] = p;
    }
    __syncthreads();
    if (tid < kN){
        shz[tid] = shpart[0][tid] + shpart[1][tid] + shpart[2][tid] + shpart[3][tid];
    } else if (tid >= 64 && tid < 64 + kN){
        int n = tid - 64;
        shzb[n] = tanhf(shsWs[n] + shgH[n])*shwh[n];
    }
    __syncthreads();
    if (tid < 64){
        float val;
        if (tid < kN) val = shz[tid];
        else if (tid == kN){ float a = 0.f; for (int n2 = 0; n2 < kN; ++n2) a += shzb[n2]; val = a; }
        else val = -1e30f;
        float mx = val;
        #pragma unroll
        for (int o = 32; o > 0; o >>= 1) mx = fmaxf(mx, __shfl_xor(mx, o));
        float e = (tid <= kN) ? expf(val - mx) : 0.f;
        float ssum = e;
        #pragma unroll
        for (int o = 32; o > 0; o >>= 1) ssum += __shfl_xor(ssum, o);
        float a = e/ssum;
        if (tid <= kN) shalpha[tid] = a;
        if (tid < kN) attn_out[((size_t)b*kT + t)*kN + tid] = a;
    }
    __syncthreads();
    for (int d = tid; d < kD; d += 256){
        float acc = shalpha[kN]*shS[d];
        const float* vf = Vf + (size_t)b*kN*kD + d;
        #pragma unroll
        for (int n2 = 0; n2 < kN; ++n2) acc += shalpha[n2]*vf[(size_t)n2*kD];
        shHc[d] = shH[d] + acc;
    }
    __syncthreads();
    for (int d = tid; d < kD; d += 256){
        float acc = bfc[d];
        const float* w = Wfc + (size_t)d*kD;
        #pragma unroll 8
        for (int k = 0; k < kD; ++k) acc += shHc[k]*w[k];
        out_bf[((size_t)t*kB + b)*kD + d] = f2b(tanhf(acc));
    }
}

// in-place log-softmax (online max+sum, 2 memory passes)
__global__ __launch_bounds__(256) void logsoftmax_k(float* __restrict__ logits)
{
    const int row = blockIdx.x, tid = threadIdx.x;
    float* L = logits + (size_t)row*kV;
    __shared__ float rm[256], rs[256];
    float m = -1e30f, s = 0.f;
    for (int v = tid*4; v < kV; v += 1024){
        f32x4v x = *(const f32x4v*)(L + v);
        #pragma unroll
        for (int j = 0; j < 4; ++j){
            float nm = fmaxf(m, x[j]);
            s = s*__expf(m - nm) + __expf(x[j] - nm);
            m = nm;
        }
    }
    rm[tid] = m; rs[tid] = s; __syncthreads();
    for (int st = 128; st > 0; st >>= 1){
        if (tid < st){
            float m2 = rm[tid + st], s2 = rs[tid + st];
            float nm = fmaxf(rm[tid], m2);
            rs[tid] = rs[tid]*__expf(rm[tid] - nm) + s2*__expf(m2 - nm);
            rm[tid] = nm;
        }
        __syncthreads();
    }
    float lse = rm[0] + logf(rs[0]);
    for (int v = tid*4; v < kV; v += 1024){
        f32x4v x = *(const f32x4v*)(L + v);
        x[0] -= lse; x[1] -= lse; x[2] -= lse; x[3] -= lse;
        *(f32x4v*)(L + v) = x;
    }
}

extern "C" void kernel_launch(void* const* d_in, const int* in_sizes, int n_in,
                              void* d_out, int out_size, void* d_ws, size_t ws_size,
                              hipStream_t stream)
{
    const float* img   = (const float*)d_in[0];
    const int*   target= (const int*)  d_in[1];
    const float* emb   = (const float*)d_in[2];
    const float* Wa    = (const float*)d_in[3];
    const float* ba    = (const float*)d_in[4];
    const float* Wb    = (const float*)d_in[5];
    const float* bb    = (const float*)d_in[6];
    const float* Whi   = (const float*)d_in[7];
    const float* bhi   = (const float*)d_in[8];
    const float* Wmi   = (const float*)d_in[9];
    const float* bmi   = (const float*)d_in[10];
    const float* Wih   = (const float*)d_in[11];
    const float* bih   = (const float*)d_in[12];
    const float* Whh   = (const float*)d_in[13];
    const float* bhh   = (const float*)d_in[14];
    const float* Wv    = (const float*)d_in[15];
    const float* Wg    = (const float*)d_in[16];
    const float* wh    = (const float*)d_in[17];
    const float* W_H   = (const float*)d_in[18];
    const float* Wx    = (const float*)d_in[19];
    const float* Wh2   = (const float*)d_in[20];
    const float* Wsm   = (const float*)d_in[21];
    const float* Wc    = (const float*)d_in[22];
    const float* bc    = (const float*)d_in[23];
    const float* Wfc   = (const float*)d_in[24];
    const float* bfc   = (const float*)d_in[25];
    const float* Wp    = (const float*)d_in[26];
    const float* bp    = (const float*)d_in[27];
    (void)in_sizes; (void)n_in; (void)out_size; (void)ws_size;

    float* out0 = (float*)d_out;                       // [B*T, V] logprobs (rows b*T+t)
    float* attn_out = out0 + (size_t)kB*kT*kV;         // [B, T, N]

    char* base = (char*)d_ws;
    size_t off = 0;
    auto allocf = [&](size_t n)->float*{
        float* p = (float*)(base + off);
        off += ((n*sizeof(float) + 255) & ~(size_t)255);
        return p;
    };
    auto allocb = [&](size_t n)->u16*{
        u16* p = (u16*)(base + off);
        off += ((n*sizeof(u16) + 255) & ~(size_t)255);
        return p;
    };
    // fp32 scratch
    float* meanb  = allocf((size_t)kB*kC);
    float* initC  = allocf((size_t)kB*1536);           // [vg | h0 | m0]
    float* Vf     = allocf((size_t)kB*kN*kD);
    float* zbase  = allocf((size_t)kB*kN*kN);
    float* gxbase = allocf((size_t)kB*2048);
    float* gtbase = allocf((size_t)kB*512);
    float* bsum   = allocf(2048);
    float* bcat3  = allocf(1536);
    float* bHC    = allocf(1024);
    float* xall   = allocf((size_t)kT*kB*2560);        // per-t bases [t][b][2560]
    float* gates  = allocf((size_t)kB*2560);
    float* mbuf0  = allocf((size_t)kB*kD);
    float* mbuf1  = allocf((size_t)kB*kD);
    float* HS     = allocf((size_t)kB*1024);
    // bf16 scratch
    u16* Wa_bf    = allocb((size_t)kD*kC);
    u16* Wv_bf    = allocb((size_t)kN*kD);
    u16* Wrec_bf  = allocb((size_t)2560*kD);           // [Whh ; Wh2]
    u16* Wih_bf   = allocb((size_t)2048*1024);
    u16* Wx_bf    = allocb((size_t)512*1024);
    u16* Winit_bf = allocb((size_t)1536*kC);           // [Wb ; Whi ; Wmi]
    u16* Wp_bf    = allocb((size_t)kV*kD);
    u16* WHC_bf   = allocb((size_t)1024*kD);           // [WH ; Wc]
    u16* Vf_bf    = allocb((size_t)kB*kN*kD);
    u16* init_bf  = allocb((size_t)kB*1536);
    u16* we_bf    = allocb((size_t)kT*kB*kE);
    u16* hbf      = allocb((size_t)kB*kD);
    u16* gtvbf    = allocb((size_t)kB*kD);
    u16* outbf    = allocb((size_t)kT*kB*kD);

    auto cvt = [&](const float* s, u16* d, size_t n){
        int n4 = (int)(n/4);
        f2bf_k<<<(n4+255)/256, 256, 0, stream>>>(s, d, n4);
    };
    auto G = [&](const void* A, const void* A2, int nsplit, int lda, int af32,
                 const u16* W, int ldw, float* C, int ldc, u16* Cbf,
                 int M, int N, int K, const float* bias,
                 const float* a1, int l1, int a1mask, int act, int rowmap){
        dim3 g((N + TBN - 1)/TBN, (M + TBM - 1)/TBM);
        gemm_bf16<<<g, 256, 0, stream>>>(A, A2, nsplit, lda, af32, W, ldw, C, ldc, Cbf,
                                         M, N, K, bias, a1, l1, a1mask, act, rowmap);
    };
    const int NOSPLIT = 1 << 30;

    // ---- weight conversions (one-time cost, memory-bound) ----
    cvt(Wa,  Wa_bf,  (size_t)kD*kC);
    cvt(Wv,  Wv_bf,  (size_t)kN*kD);
    cvt(Whh, Wrec_bf, (size_t)2048*kD);
    cvt(Wh2, Wrec_bf + (size_t)2048*kD, (size_t)512*kD);
    cvt(Wih, Wih_bf, (size_t)2048*1024);
    cvt(Wx,  Wx_bf,  (size_t)512*1024);
    cvt(Wb,  Winit_bf, (size_t)512*kC);
    cvt(Whi, Winit_bf + (size_t)512*kC, (size_t)512*kC);
    cvt(Wmi, Winit_bf + (size_t)1024*kC, (size_t)512*kC);
    cvt(Wp,  Wp_bf,  (size_t)kV*kD);
    cvt(W_H, WHC_bf, (size_t)512*kD);
    cvt(Wc,  WHC_bf + (size_t)512*kD, (size_t)512*kD);
    // ---- bias prep ----
    bsum_k<<<8, 256, 0, stream>>>(bih, bhh, bsum, 2048);
    copy_k<<<2, 256, 0, stream>>>(bb,  bcat3, 512);
    copy_k<<<2, 256, 0, stream>>>(bhi, bcat3 + 512, 512);
    copy_k<<<2, 256, 0, stream>>>(bmi, bcat3 + 1024, 512);
    zero_k<<<2, 256, 0, stream>>>(bHC, 512);
    copy_k<<<2, 256, 0, stream>>>(bc, bHC + 512, 512);

    // ---- precompute ----
    mean_k<<<kB*kC/256, 256, 0, stream>>>(img, meanb);
    emb_gather_k<<<kT*kB*kE/256, 256, 0, stream>>>(target, emb, we_bf);
    // [vg|h0|m0] = relu(mean @ [Wb;Whi;Wmi]^T + bcat3)
    G(meanb, meanb, NOSPLIT, kC, 1, Winit_bf, kC, initC, 1536, init_bf,
      kB, 1536, kC, bcat3, nullptr, 0, -1, 1, 0);
    // Vf = relu(img @ Wa^T + ba)
    G(img, img, NOSPLIT, kC, 1, Wa_bf, kC, Vf, kD, Vf_bf,
      kB*kN, kD, kC, ba, nullptr, 0, -1, 1, 0);
    // zbase = Vf @ Wv^T
    G(Vf_bf, Vf_bf, NOSPLIT, kD, 0, Wv_bf, kD, zbase, kN, nullptr,
      kB*kN, kN, kD, nullptr, nullptr, 0, -1, 0, 0);
    // gxbase = vg @ Wih[:, :D]^T + (bih+bhh); gtbase = vg @ Wx[:, :D]^T
    G(init_bf, init_bf, NOSPLIT, 1536, 0, Wih_bf, 1024, gxbase, 2048, nullptr,
      kB, 2048, kD, bsum, nullptr, 0, -1, 0, 0);
    G(init_bf, init_bf, NOSPLIT, 1536, 0, Wx_bf, 1024, gtbase, 512, nullptr,
      kB, 512, kD, nullptr, nullptr, 0, -1, 0, 0);
    // xall[:, :2048] = we @ Wih[:, D:]^T + gxbase[b];  xall[:, 2048:] = we @ Wx[:, D:]^T + gtbase[b]
    G(we_bf, we_bf, NOSPLIT, kE, 0, Wih_bf + 512, 1024, xall, 2560, nullptr,
      kT*kB, 2048, kE, nullptr, gxbase, 2048, 127, 0, 0);
    G(we_bf, we_bf, NOSPLIT, kE, 0, Wx_bf + 512, 1024, xall + 2048, 2560, nullptr,
      kT*kB, 512, kE, nullptr, gtbase, 512, 127, 0, 0);

    // ---- recurrent scan: 4 launches/step ----
    for (int t = 0; t < kT; ++t){
        const u16* hA  = (t == 0) ? (init_bf + 512) : hbf;
        int ldh        = (t == 0) ? 1536 : 512;
        const float* mIn = (t == 0) ? (initC + 1024) : ((t & 1) ? mbuf0 : mbuf1);
        int ldm        = (t == 0) ? 1536 : 512;
        float* mOut    = (t & 1) ? mbuf1 : mbuf0;
        // gates|gtpre = h @ [Whh;Wh2]^T + xall[t]
        G(hA, hA, NOSPLIT, ldh, 0, Wrec_bf, kD, gates, 2560, nullptr,
          kB, 2560, kD, nullptr, xall + (size_t)t*kB*2560, 2560, -1, 0, 0);
        lstm_k<<<kB*kD/256, 256, 0, stream>>>(gates, mIn, ldm, mOut, hbf, gtvbf);
        // [H|s] = relu([h2;gtv] @ [WH;Wc]^T + [0;bc])   (dual-A at col 512)
        G(hbf, gtvbf, 512, kD, 0, WHC_bf, kD, HS, 1024, nullptr,
          kB, 1024, kD, bHC, nullptr, 0, -1, 1, 0);
        attn_step<<<kB, 256, 0, stream>>>(HS, Wg, Wsm, wh, zbase, Vf, Wfc, bfc,
                                          outbf, attn_out, t);
    }

    // ---- logits (row-permuted store to b*T+t) + log_softmax ----
    G(outbf, outbf, NOSPLIT, kD, 0, Wp_bf, kD, out0, kV, nullptr,
      kT*kB, kV, kD, bp, nullptr, 0, -1, 0, 1);
    logsoftmax_k<<<kB*kT, 256, 0, stream>>>(out0);
}

// Round 4
// 2244.510 us; speedup vs baseline: 2.4735x; 1.5289x over previous
//
#include <hip/hip_runtime.h>
#include <hip/hip_bf16.h>

// Problem dims
static const int kB = 128, kN = 49, kC = 2048, kD = 512, kE = 512, kV = 10000, kT = 20;

typedef __bf16 bf16x8 __attribute__((ext_vector_type(8)));
typedef float  f32x4v __attribute__((ext_vector_type(4)));
typedef _Float16 h8_t __attribute__((ext_vector_type(8)));
typedef unsigned short u16;
typedef unsigned int u32;

__device__ __forceinline__ float sigmoidf_(float x){ return 1.f/(1.f+expf(-x)); }
__device__ __forceinline__ u16 f2b(float x){ __hip_bfloat16 h = __float2bfloat16(x); return *(u16*)&h; }
__device__ __forceinline__ float bu2f(u32 u){ u32 w = u << 16; union{u32 u; float f;} c; c.u = w; return c.f; }

// ================= bf16 MFMA NT GEMM =================
// C[M,N] = act(A[M,K]@W[N,K]^T + bias + add1[m&a1mask]), fp32 acc.
// C (fp32) and Cbf (bf16) both optional.
#define TBM 128
#define TBN 128
#define TBK 32

__global__ __launch_bounds__(256) void gemm_bf16(
    const u16* __restrict__ A, int lda,
    const u16* __restrict__ W, int ldw,
    float* __restrict__ C, u16* __restrict__ Cbf, int ldc,
    int M, int N, int K,
    const float* __restrict__ bias,
    const float* __restrict__ add1, int ld1, int a1mask,
    int act)
{
    __shared__ __align__(16) u16 As[TBM*TBK];
    __shared__ __align__(16) u16 Bs[TBN*TBK];
    const int tid = threadIdx.x;
    const int bm = blockIdx.y * TBM;
    const int bn = blockIdx.x * TBN;
    const int wave = tid >> 6, lane = tid & 63;
    const int wm = (wave >> 1) * 64, wn = (wave & 1) * 64;
    const int lm = lane & 15, quad = lane >> 4;
    const int r = tid >> 2, koff = (tid & 3) * 8;
    f32x4v acc[4][4] = {};
    for (int k0 = 0; k0 < K; k0 += TBK) {
        #pragma unroll
        for (int h = 0; h < 2; ++h) {
            int row = r + h*64;
            bf16x8 av = {};
            int gm = bm + row;
            if (gm < M) av = *(const bf16x8*)(A + (size_t)gm*lda + k0 + koff);
            *(bf16x8*)&As[row*TBK + koff] = av;
            bf16x8 wv = {};
            int gn = bn + row;
            if (gn < N) wv = *(const bf16x8*)(W + (size_t)gn*ldw + k0 + koff);
            *(bf16x8*)&Bs[row*TBK + koff] = wv;
        }
        __syncthreads();
        bf16x8 afr[4], bfr[4];
        #pragma unroll
        for (int i = 0; i < 4; ++i) afr[i] = *(const bf16x8*)&As[(wm + i*16 + lm)*TBK + quad*8];
        #pragma unroll
        for (int j = 0; j < 4; ++j) bfr[j] = *(const bf16x8*)&Bs[(wn + j*16 + lm)*TBK + quad*8];
        #pragma unroll
        for (int i = 0; i < 4; ++i)
            #pragma unroll
            for (int j = 0; j < 4; ++j)
                acc[i][j] = __builtin_amdgcn_mfma_f32_16x16x32_bf16(afr[i], bfr[j], acc[i][j], 0, 0, 0);
        __syncthreads();
    }
    #pragma unroll
    for (int i = 0; i < 4; ++i) {
        int mbase = bm + wm + i*16 + quad*4;
        #pragma unroll
        for (int j = 0; j < 4; ++j) {
            int n = bn + wn + j*16 + lm;
            if (n >= N) continue;
            float bv = bias ? bias[n] : 0.f;
            #pragma unroll
            for (int rr2 = 0; rr2 < 4; ++rr2) {
                int m = mbase + rr2;
                if (m >= M) continue;
                float v = acc[i][j][rr2] + bv;
                if (add1) v += add1[(size_t)(m & a1mask)*ld1 + n];
                if (act == 1) v = fmaxf(v, 0.f);
                else if (act == 2) v = tanhf(v);
                if (C)   C[(size_t)m*ldc + n] = v;
                if (Cbf) Cbf[(size_t)m*ldc + n] = f2b(v);
            }
        }
    }
}

// ================= conversion / prep kernels =================
// fp32 [rows][src_ld] (first K cols) -> bf16 [rows][K]
__global__ __launch_bounds__(256) void cvt2d_k(const float* __restrict__ src, int src_ld, int K,
                                               int rows, u16* __restrict__ dst){
    int idx = blockIdx.x*256 + threadIdx.x;
    int kc8 = K >> 3;
    if (idx >= rows*kc8) return;
    int rr = idx / kc8, kc = idx - rr*kc8;
    const float* p = src + (size_t)rr*src_ld + kc*8;
    f32x4v f0 = *(const f32x4v*)p, f1 = *(const f32x4v*)(p+4);
    union { u16 u[8]; uint4 v; } pk;
    pk.u[0]=f2b(f0[0]); pk.u[1]=f2b(f0[1]); pk.u[2]=f2b(f0[2]); pk.u[3]=f2b(f0[3]);
    pk.u[4]=f2b(f1[0]); pk.u[5]=f2b(f1[1]); pk.u[6]=f2b(f1[2]); pk.u[7]=f2b(f1[3]);
    *(uint4*)(dst + (size_t)rr*K + kc*8) = pk.v;
}

// fp32 [rows][src_ld] (K=512) -> f16 interleaved [k/8][Ntot][8] at row offset n_off
__global__ __launch_bounds__(256) void cvt_il_k(const float* __restrict__ src, int src_ld,
                                                int rows, int n_off, int Ntot,
                                                _Float16* __restrict__ dst){
    int idx = blockIdx.x*256 + threadIdx.x;
    if (idx >= rows*64) return;
    int rr = idx >> 6, kc = idx & 63;
    const float* p = src + (size_t)rr*src_ld + kc*8;
    f32x4v f0 = *(const f32x4v*)p, f1 = *(const f32x4v*)(p+4);
    h8_t o;
    o[0]=(_Float16)f0[0]; o[1]=(_Float16)f0[1]; o[2]=(_Float16)f0[2]; o[3]=(_Float16)f0[3];
    o[4]=(_Float16)f1[0]; o[5]=(_Float16)f1[1]; o[6]=(_Float16)f1[2]; o[7]=(_Float16)f1[3];
    *(h8_t*)&dst[((size_t)kc*Ntot + n_off + rr)*8] = o;
}

// bias2560 = [bih+bhh (2048); 0 (512)]; bcat3 = [bb|bhi|bmi]
__global__ __launch_bounds__(256) void bias_prep_k(const float* bih, const float* bhh,
                                                   const float* bb, const float* bhi, const float* bmi,
                                                   float* bias2560, float* bcat3){
    int i = blockIdx.x*256 + threadIdx.x;
    if (i < 2048) bias2560[i] = bih[i] + bhh[i];
    else if (i < 2560) bias2560[i] = 0.f;
    else if (i < 4096){
        int j = i - 2560;
        bcat3[j] = (j < 512) ? bb[j] : (j < 1024 ? bhi[j-512] : bmi[j-1024]);
    }
}

__global__ __launch_bounds__(256) void mean_k(const float* __restrict__ img, u16* __restrict__ meanp){
    int idx = blockIdx.x*256 + threadIdx.x;       // B*C
    int b = idx >> 11, c = idx & (kC-1);
    const float* p = img + (size_t)b*kN*kC + c;
    float s = 0.f;
    #pragma unroll
    for (int n = 0; n < kN; ++n) s += p[(size_t)n*kC];
    meanp[idx] = f2b(s * (1.f/(float)kN));
}

// we[t*B+b][e] bf16
__global__ __launch_bounds__(256) void emb_gather_k(const int* __restrict__ target,
                                                    const float* __restrict__ emb,
                                                    u16* __restrict__ we){
    int idx = blockIdx.x*256 + threadIdx.x;       // T*B*E
    int e = idx & (kE-1);
    int rr = idx >> 9;                            // t*B + b
    int b = rr & 127, t = rr >> 7;
    float v = 0.f;
    if (t > 0){ int tok = target[b*kT + (t-1)]; v = emb[(size_t)tok*kE + e]; }
    we[idx] = f2b(v);
}

// ================= persistent per-batch scan =================
__device__ __forceinline__ float dot8f(h8_t a, h8_t b, float c){
    #pragma unroll
    for (int i = 0; i < 8; ++i) c = fmaf((float)a[i], (float)b[i], c);
    return c;
}

__global__ __launch_bounds__(512, 1) void scan_k(
    const float* __restrict__ initC,       // [128][1536] vg|h0|m0 (fp32)
    const u16* __restrict__ Vf_bf,         // [128*49][512]
    const float* __restrict__ zbase,       // [128][49][49]
    const float* __restrict__ xall,        // [20][128][2560]
    const _Float16* __restrict__ Wrec,     // il [64][2560][8]
    const _Float16* __restrict__ WHC,      // il [64][1024][8]
    const _Float16* __restrict__ WgWs,     // il [64][98][8]
    const _Float16* __restrict__ Wfc,      // il [64][512][8]
    const float* __restrict__ bc,
    const float* __restrict__ bfc,
    const float* __restrict__ wh,
    u16* __restrict__ outbf,               // [20*128][512] bf16
    float* __restrict__ attn_out)          // [128][20][49] fp32
{
    const int b = blockIdx.x, tid = threadIdx.x;
    __shared__ __align__(16) _Float16 sh[512];     // h (f16), also h2 after lstm
    __shared__ __align__(16) _Float16 sgtv[512];
    __shared__ __align__(16) _Float16 sHc[512];
    __shared__ __align__(16) _Float16 sVf[49*512];
    __shared__ float szb[49*49];
    __shared__ float sH[512], ss[512];
    __shared__ float sbc[512], sbfc[512];
    __shared__ float swh[64], sgH[64], ssWs[64], szv[64];
    __shared__ float spart[8][64];
    __shared__ float salpha[52];

    // ---- stage per-batch constants ----
    {
        const uint4* src = (const uint4*)(Vf_bf + (size_t)b*49*512);
        for (int c = tid; c < 49*512/8; c += 512){
            uint4 v = src[c];
            h8_t o;
            o[0]=(_Float16)bu2f(v.x & 0xffff); o[1]=(_Float16)bu2f(v.x >> 16);
            o[2]=(_Float16)bu2f(v.y & 0xffff); o[3]=(_Float16)bu2f(v.y >> 16);
            o[4]=(_Float16)bu2f(v.z & 0xffff); o[5]=(_Float16)bu2f(v.z >> 16);
            o[6]=(_Float16)bu2f(v.w & 0xffff); o[7]=(_Float16)bu2f(v.w >> 16);
            *(h8_t*)&sVf[c*8] = o;
        }
    }
    for (int i = tid; i < 49*49; i += 512) szb[i] = zbase[(size_t)b*2401 + i];
    if (tid < 64) swh[tid] = (tid < 49) ? wh[tid] : 0.f;
    sbc[tid] = bc[tid]; sbfc[tid] = bfc[tid];
    sh[tid] = (_Float16)initC[(size_t)b*1536 + 512 + tid];
    float m_reg = initC[(size_t)b*1536 + 1024 + tid];
    __syncthreads();

    for (int t = 0; t < kT; ++t){
        // ---- Phase A: gates GEMV (thread tid -> outputs tid+512j, j=0..4) ----
        float acc[5];
        {
            const float* xrow = xall + ((size_t)t*kB + b)*2560;
            #pragma unroll
            for (int j = 0; j < 5; ++j) acc[j] = xrow[tid + 512*j];
            for (int kc = 0; kc < 64; ++kc){
                h8_t hv = *(const h8_t*)&sh[kc*8];
                const _Float16* wb = Wrec + (size_t)kc*2560*8;
                #pragma unroll
                for (int j = 0; j < 5; ++j){
                    h8_t wv = *(const h8_t*)&wb[(size_t)(tid + 512*j)*8];
                    acc[j] = dot8f(hv, wv, acc[j]);
                }
            }
        }
        // ---- LSTM pointwise (thread-local) ----
        float i_g = sigmoidf_(acc[0]);
        float f_g = sigmoidf_(acc[1]);
        float g_g = tanhf(acc[2]);
        float o_g = sigmoidf_(acc[3]);
        m_reg = f_g*m_reg + i_g*g_g;
        float tm = tanhf(m_reg);
        float h2v = o_g*tm;
        float gtvv = sigmoidf_(acc[4])*tm;
        __syncthreads();                      // phase-A reads of sh complete
        sh[tid] = (_Float16)h2v;
        sgtv[tid] = (_Float16)gtvv;
        __syncthreads();
        // ---- Phase B: H = relu(h2@WH^T), s = relu(gtv@Wc^T + bc) ----
        {
            float aH = 0.f, aS = 0.f;
            for (int kc = 0; kc < 64; ++kc){
                h8_t hv = *(const h8_t*)&sh[kc*8];
                h8_t gv = *(const h8_t*)&sgtv[kc*8];
                const _Float16* wb = WHC + (size_t)kc*1024*8;
                h8_t w1 = *(const h8_t*)&wb[(size_t)tid*8];
                h8_t w2 = *(const h8_t*)&wb[(size_t)(512 + tid)*8];
                aH = dot8f(hv, w1, aH);
                aS = dot8f(gv, w2, aS);
            }
            sH[tid] = fmaxf(aH, 0.f);
            ss[tid] = fmaxf(aS + sbc[tid], 0.f);
        }
        __syncthreads();
        // ---- Phase C1: gH[n]=H.Wg[n] (lanes 0-48), sWs[n]=s.Ws[n] (lanes 64-112) ----
        if (tid < 49){
            float a = 0.f;
            for (int kc = 0; kc < 64; ++kc){
                h8_t w = *(const h8_t*)&WgWs[((size_t)kc*98 + tid)*8];
                #pragma unroll
                for (int j = 0; j < 8; ++j) a = fmaf((float)w[j], sH[kc*8 + j], a);
            }
            sgH[tid] = a;
        } else if (tid >= 64 && tid < 64 + 49){
            int n = tid - 64;
            float a = 0.f;
            for (int kc = 0; kc < 64; ++kc){
                h8_t w = *(const h8_t*)&WgWs[((size_t)kc*98 + 49 + n)*8];
                #pragma unroll
                for (int j = 0; j < 8; ++j) a = fmaf((float)w[j], ss[kc*8 + j], a);
            }
            ssWs[n] = a;
        }
        __syncthreads();
        // ---- Phase C2: z[n] = sum_k tanh(zb[n][k]+gH[k])*wh[k] (8-way k-split) ----
        {
            int n = tid & 63, j = tid >> 3 >> 3;  // j = tid>>6
            j = tid >> 6;
            float p = 0.f;
            if (n < 49){
                const float* zb = &szb[n*49];
                for (int k = j; k < 49; k += 8) p += tanhf(zb[k] + sgH[k])*swh[k];
            }
            spart[j][n] = p;
        }
        __syncthreads();
        if (tid < 49){
            float z = 0.f;
            #pragma unroll
            for (int j = 0; j < 8; ++j) z += spart[j][tid];
            szv[tid] = z;
        } else if (tid == 56){
            float a = 0.f;
            for (int n = 0; n < 49; ++n) a += tanhf(ssWs[n] + sgH[n])*swh[n];
            szv[49] = a;
        }
        __syncthreads();
        // ---- softmax over 50 (wave 0) ----
        if (tid < 64){
            float val = (tid < 50) ? szv[tid] : -1e30f;
            float mx = val;
            #pragma unroll
            for (int o = 32; o > 0; o >>= 1) mx = fmaxf(mx, __shfl_xor(mx, o));
            float e = (tid < 50) ? __expf(val - mx) : 0.f;
            float ssum = e;
            #pragma unroll
            for (int o = 32; o > 0; o >>= 1) ssum += __shfl_xor(ssum, o);
            float a = e/ssum;
            if (tid < 50) salpha[tid] = a;
            if (tid < 49) attn_out[((size_t)b*kT + t)*kN + tid] = a;
        }
        __syncthreads();
        // ---- Phase C3: ctx + Hc ----
        {
            float a = salpha[49]*ss[tid];
            #pragma unroll
            for (int n = 0; n < 49; ++n) a = fmaf(salpha[n], (float)sVf[n*512 + tid], a);
            sHc[tid] = (_Float16)(sH[tid] + a);
        }
        __syncthreads();
        // ---- Phase D: out = tanh(Hc@Wfc^T + bfc) ----
        {
            float a = sbfc[tid];
            for (int kc = 0; kc < 64; ++kc){
                h8_t hc = *(const h8_t*)&sHc[kc*8];
                h8_t w  = *(const h8_t*)&Wfc[((size_t)kc*512 + tid)*8];
                a = dot8f(hc, w, a);
            }
            outbf[((size_t)t*kB + b)*512 + tid] = f2b(tanhf(a));
        }
        __syncthreads();
    }
}

// ================= log-softmax: read bf16 logits row (t*128+b), write fp32 row (b*20+t) =================
__global__ __launch_bounds__(256) void logsoftmax_k(const u16* __restrict__ logits_bf,
                                                    float* __restrict__ out0)
{
    const int r = blockIdx.x, tid = threadIdx.x;   // r = b*20+t
    const int b = r / 20, t = r - b*20;
    const u16* L = logits_bf + (size_t)(t*kB + b)*kV;
    __shared__ float rm[256], rs[256];
    float m = -1e30f, s = 0.f;
    for (int c = tid; c < kV/8; c += 256){
        uint4 v = *(const uint4*)(L + c*8);
        u32 w[4] = {v.x, v.y, v.z, v.w};
        #pragma unroll
        for (int j = 0; j < 4; ++j){
            float x0 = bu2f(w[j] & 0xffff), x1 = bu2f(w[j] >> 16);
            float nm = fmaxf(m, fmaxf(x0, x1));
            s = s*__expf(m - nm) + __expf(x0 - nm) + __expf(x1 - nm);
            m = nm;
        }
    }
    rm[tid] = m; rs[tid] = s; __syncthreads();
    for (int st = 128; st > 0; st >>= 1){
        if (tid < st){
            float m2 = rm[tid + st], s2 = rs[tid + st];
            float nm = fmaxf(rm[tid], m2);
            rs[tid] = rs[tid]*__expf(rm[tid] - nm) + s2*__expf(m2 - nm);
            rm[tid] = nm;
        }
        __syncthreads();
    }
    float lse = rm[0] + logf(rs[0]);
    float* D = out0 + (size_t)r*kV;
    for (int c = tid; c < kV/8; c += 256){
        uint4 v = *(const uint4*)(L + c*8);
        u32 w[4] = {v.x, v.y, v.z, v.w};
        f32x4v o0, o1;
        o0[0]=bu2f(w[0]&0xffff)-lse; o0[1]=bu2f(w[0]>>16)-lse;
        o0[2]=bu2f(w[1]&0xffff)-lse; o0[3]=bu2f(w[1]>>16)-lse;
        o1[0]=bu2f(w[2]&0xffff)-lse; o1[1]=bu2f(w[2]>>16)-lse;
        o1[2]=bu2f(w[3]&0xffff)-lse; o1[3]=bu2f(w[3]>>16)-lse;
        *(f32x4v*)(D + c*8) = o0;
        *(f32x4v*)(D + c*8 + 4) = o1;
    }
}

extern "C" void kernel_launch(void* const* d_in, const int* in_sizes, int n_in,
                              void* d_out, int out_size, void* d_ws, size_t ws_size,
                              hipStream_t stream)
{
    const float* img   = (const float*)d_in[0];
    const int*   target= (const int*)  d_in[1];
    const float* emb   = (const float*)d_in[2];
    const float* Wa    = (const float*)d_in[3];
    const float* ba    = (const float*)d_in[4];
    const float* Wb    = (const float*)d_in[5];
    const float* bb    = (const float*)d_in[6];
    const float* Whi   = (const float*)d_in[7];
    const float* bhi   = (const float*)d_in[8];
    const float* Wmi   = (const float*)d_in[9];
    const float* bmi   = (const float*)d_in[10];
    const float* Wih   = (const float*)d_in[11];
    const float* bih   = (const float*)d_in[12];
    const float* Whh   = (const float*)d_in[13];
    const float* bhh   = (const float*)d_in[14];
    const float* Wv    = (const float*)d_in[15];
    const float* Wg    = (const float*)d_in[16];
    const float* wh    = (const float*)d_in[17];
    const float* W_H   = (const float*)d_in[18];
    const float* Wx    = (const float*)d_in[19];
    const float* Wh2   = (const float*)d_in[20];
    const float* Wsm   = (const float*)d_in[21];
    const float* Wc    = (const float*)d_in[22];
    const float* bc    = (const float*)d_in[23];
    const float* Wfc   = (const float*)d_in[24];
    const float* bfc   = (const float*)d_in[25];
    const float* Wp    = (const float*)d_in[26];
    const float* bp    = (const float*)d_in[27];
    (void)in_sizes; (void)n_in; (void)out_size; (void)ws_size;

    float* out0 = (float*)d_out;                       // [B*T, V] logprobs (row b*20+t)
    float* attn_out = out0 + (size_t)kB*kT*kV;         // [B, T, N]

    char* base = (char*)d_ws;
    size_t off = 0;
    auto alloc = [&](size_t bytes)->char*{
        char* p = base + off;
        off += ((bytes + 255) & ~(size_t)255);
        return p;
    };
    // fixed region
    u16* Wa_bf     = (u16*)alloc((size_t)kD*kC*2);
    u16* Winit_bf  = (u16*)alloc((size_t)1536*kC*2);
    u16* Wv_bf     = (u16*)alloc((size_t)kN*kD*2);
    u16* Wp_bf     = (u16*)alloc((size_t)kV*kD*2);
    u16* Wfirst_bf = (u16*)alloc((size_t)2560*512*2); // [Wih[:, :512]; Wx[:, :512]]
    u16* Wlast_bf  = (u16*)alloc((size_t)2560*512*2); // [Wih[:, 512:]; Wx[:, 512:]]
    _Float16* Wrec_il = (_Float16*)alloc((size_t)2560*512*2);
    _Float16* WHC_il  = (_Float16*)alloc((size_t)1024*512*2);
    _Float16* WgWs_il = (_Float16*)alloc((size_t)98*512*2);
    _Float16* Wfc_il  = (_Float16*)alloc((size_t)512*512*2);
    float* bias2560 = (float*)alloc(2560*4);
    float* bcat3    = (float*)alloc(1536*4);
    u16* meanb_bf   = (u16*)alloc((size_t)kB*kC*2);
    float* initC    = (float*)alloc((size_t)kB*1536*4);
    u16* init_bf    = (u16*)alloc((size_t)kB*1536*2);
    u16* Vf_bf      = (u16*)alloc((size_t)kB*kN*kD*2);
    float* zbase    = (float*)alloc((size_t)kB*kN*kN*4);
    u16* we_bf      = (u16*)alloc((size_t)kT*kB*kE*2);
    float* gbase    = (float*)alloc((size_t)kB*2560*4);
    u16* outbf      = (u16*)alloc((size_t)kT*kB*kD*2);
    // dynamic region: img_bf + xall early; logits_bf (aliases) late
    char* dyn = base + off;
    u16* img_bf    = (u16*)dyn;                                   // 25.7 MB
    float* xall    = (float*)(dyn + ((size_t)kB*kN*kC*2 + 255 & ~(size_t)255)); // 26.2 MB
    u16* logits_bf = (u16*)dyn;                                   // 51.2 MB (after scan)

    auto G = [&](const u16* A, int lda, const u16* W, int ldw,
                 float* C, u16* Cbf, int ldc, int M, int N, int K,
                 const float* bias, const float* a1, int l1, int a1mask, int act){
        dim3 g((N + TBN - 1)/TBN, (M + TBM - 1)/TBM);
        gemm_bf16<<<g, 256, 0, stream>>>(A, lda, W, ldw, C, Cbf, ldc, M, N, K,
                                         bias, a1, l1, a1mask, act);
    };
    auto CV = [&](const float* src, int src_ld, int K, int rows, u16* dst){
        int n = rows*(K/8);
        cvt2d_k<<<(n + 255)/256, 256, 0, stream>>>(src, src_ld, K, rows, dst);
    };
    auto IL = [&](const float* src, int rows, int n_off, int Ntot, _Float16* dst){
        int n = rows*64;
        cvt_il_k<<<(n + 255)/256, 256, 0, stream>>>(src, 512, rows, n_off, Ntot, dst);
    };

    // ---- prep ----
    bias_prep_k<<<16, 256, 0, stream>>>(bih, bhh, bb, bhi, bmi, bias2560, bcat3);
    mean_k<<<kB*kC/256, 256, 0, stream>>>(img, meanb_bf);
    emb_gather_k<<<kT*kB*kE/256, 256, 0, stream>>>(target, emb, we_bf);
    CV(img, kC, kC, kB*kN, img_bf);
    CV(Wa,  kC, kC, kD, Wa_bf);
    CV(Wb,  kC, kC, kD, Winit_bf);
    CV(Whi, kC, kC, kD, Winit_bf + (size_t)512*kC);
    CV(Wmi, kC, kC, kD, Winit_bf + (size_t)1024*kC);
    CV(Wv,  kD, kD, kN, Wv_bf);
    CV(Wp,  kD, kD, kV, Wp_bf);
    CV(Wih,       1024, 512, 2048, Wfirst_bf);
    CV(Wx,        1024, 512, 512,  Wfirst_bf + (size_t)2048*512);
    CV(Wih + 512, 1024, 512, 2048, Wlast_bf);
    CV(Wx  + 512, 1024, 512, 512,  Wlast_bf + (size_t)2048*512);
    IL(Whh, 2048, 0,    2560, Wrec_il);
    IL(Wh2, 512,  2048, 2560, Wrec_il);
    IL(W_H, 512,  0,    1024, WHC_il);
    IL(Wc,  512,  512,  1024, WHC_il);
    IL(Wg,  49,   0,    98,   WgWs_il);
    IL(Wsm, 49,   49,   98,   WgWs_il);
    IL(Wfc, 512,  0,    512,  Wfc_il);

    // ---- precompute GEMMs ----
    // [vg|h0|m0] = relu(mean @ [Wb;Whi;Wmi]^T + bcat3)
    G(meanb_bf, kC, Winit_bf, kC, initC, init_bf, 1536, kB, 1536, kC, bcat3, nullptr, 0, -1, 1);
    // Vf = relu(img @ Wa^T + ba)  (bf16 out only)
    G(img_bf, kC, Wa_bf, kC, nullptr, Vf_bf, kD, kB*kN, kD, kC, ba, nullptr, 0, -1, 1);
    // zbase = Vf @ Wv^T (fp32)
    G(Vf_bf, kD, Wv_bf, kD, zbase, nullptr, kN, kB*kN, kN, kD, nullptr, nullptr, 0, -1, 0);
    // gbase[b] = vg @ [Wih;Wx][:, :512]^T + [bih+bhh; 0]
    G(init_bf, 1536, Wfirst_bf, 512, gbase, nullptr, 2560, kB, 2560, kD, bias2560, nullptr, 0, -1, 0);
    // xall[t*128+b] = we @ [Wih;Wx][:, 512:]^T + gbase[b]
    G(we_bf, kE, Wlast_bf, 512, xall, nullptr, 2560, kT*kB, 2560, kE, nullptr, gbase, 2560, 127, 0);

    // ---- persistent scan (one launch) ----
    scan_k<<<kB, 512, 0, stream>>>(initC, Vf_bf, zbase, xall,
                                   Wrec_il, WHC_il, WgWs_il, Wfc_il,
                                   bc, bfc, wh, outbf, attn_out);

    // ---- logits (bf16) + log-softmax -> fp32 out ----
    G(outbf, kD, Wp_bf, kD, nullptr, logits_bf, kV, kT*kB, kV, kD, bp, nullptr, 0, -1, 0);
    logsoftmax_k<<<kB*kT, 256, 0, stream>>>(logits_bf, out0);
}